// Round 1
// baseline (656.738 us; speedup 1.0000x reference)
//
#include <hip/hip_runtime.h>

#define BATCH   1024
#define MAXLEN  200
#define KCAPS   8
#define INU     256
#define OUTU    256
#define NEGPAD  -65535.0f

// ---------------- init Bcur (copy B_matrix into workspace) ----------------
__global__ void k_init(const float* __restrict__ Bm, float* __restrict__ Bcur) {
    int i = blockIdx.x * 256 + threadIdx.x;
    if (i < KCAPS * MAXLEN) Bcur[i] = Bm[i];
}

// ---------------- projection: C[M,256] = A[M,256] @ S[256,256] (fp32) ------
// block tile 128x128, thread tile 8x8 (rows rg*4+{0..3}+{0,64}, cols cg*4+{0..3}+{0,64})
#define PKT 32
#define ARS 36    // As row stride (padded) : As[128][32] -> [128][36]
#define SRS 132   // Ss row stride (padded) : Ss[32][128] -> [32][132]

__global__ __launch_bounds__(256) void k_project(const float* __restrict__ A,
                                                 const float* __restrict__ S,
                                                 float* __restrict__ C) {
    __shared__ float As[128 * ARS];
    __shared__ float Ss[PKT * SRS];
    const int tid = threadIdx.x;
    const int bm  = blockIdx.x >> 1;   // 1600 M-tiles
    const int bn  = blockIdx.x & 1;    // 2 N-tiles
    const size_t m0 = (size_t)bm * 128;
    const int    n0 = bn * 128;
    const int rg = tid >> 4;           // 0..15
    const int cg = tid & 15;           // 0..15

    float4 acc[2][2][4];
    #pragma unroll
    for (int a = 0; a < 2; a++)
        #pragma unroll
        for (int b = 0; b < 2; b++)
            #pragma unroll
            for (int i = 0; i < 4; i++)
                acc[a][b][i] = make_float4(0.f, 0.f, 0.f, 0.f);

    for (int kt = 0; kt < INU; kt += PKT) {
        __syncthreads();
        // stage A tile [128 rows][32 k]
        #pragma unroll
        for (int i = 0; i < 4; i++) {
            int q = tid + i * 256;
            int r = q >> 3, kq = q & 7;
            float4 v = *reinterpret_cast<const float4*>(&A[(m0 + r) * INU + kt + kq * 4]);
            *reinterpret_cast<float4*>(&As[r * ARS + kq * 4]) = v;
        }
        // stage S tile [32 k][128 cols]
        #pragma unroll
        for (int i = 0; i < 4; i++) {
            int q = tid + i * 256;
            int k = q >> 5, cq = q & 31;
            float4 v = *reinterpret_cast<const float4*>(&S[(size_t)(kt + k) * OUTU + n0 + cq * 4]);
            *reinterpret_cast<float4*>(&Ss[k * SRS + cq * 4]) = v;
        }
        __syncthreads();
        #pragma unroll
        for (int k4 = 0; k4 < PKT; k4 += 4) {
            float4 af[2][4];
            #pragma unroll
            for (int rh = 0; rh < 2; rh++)
                #pragma unroll
                for (int i = 0; i < 4; i++)
                    af[rh][i] = *reinterpret_cast<const float4*>(&As[(rg * 4 + rh * 64 + i) * ARS + k4]);
            #pragma unroll
            for (int kk = 0; kk < 4; kk++) {
                float4 sl = *reinterpret_cast<const float4*>(&Ss[(k4 + kk) * SRS + cg * 4]);
                float4 sh = *reinterpret_cast<const float4*>(&Ss[(k4 + kk) * SRS + 64 + cg * 4]);
                #pragma unroll
                for (int rh = 0; rh < 2; rh++)
                    #pragma unroll
                    for (int i = 0; i < 4; i++) {
                        float a = (kk == 0) ? af[rh][i].x : (kk == 1) ? af[rh][i].y
                                : (kk == 2) ? af[rh][i].z : af[rh][i].w;
                        acc[rh][0][i].x = fmaf(a, sl.x, acc[rh][0][i].x);
                        acc[rh][0][i].y = fmaf(a, sl.y, acc[rh][0][i].y);
                        acc[rh][0][i].z = fmaf(a, sl.z, acc[rh][0][i].z);
                        acc[rh][0][i].w = fmaf(a, sl.w, acc[rh][0][i].w);
                        acc[rh][1][i].x = fmaf(a, sh.x, acc[rh][1][i].x);
                        acc[rh][1][i].y = fmaf(a, sh.y, acc[rh][1][i].y);
                        acc[rh][1][i].z = fmaf(a, sh.z, acc[rh][1][i].z);
                        acc[rh][1][i].w = fmaf(a, sh.w, acc[rh][1][i].w);
                    }
            }
        }
    }
    #pragma unroll
    for (int rh = 0; rh < 2; rh++)
        #pragma unroll
        for (int i = 0; i < 4; i++) {
            size_t row = m0 + rg * 4 + rh * 64 + i;
            *reinterpret_cast<float4*>(&C[row * OUTU + n0 + cg * 4])      = acc[rh][0][i];
            *reinterpret_cast<float4*>(&C[row * OUTU + n0 + 64 + cg * 4]) = acc[rh][1][i];
        }
}

// ---------------- routing iteration: softmax -> high -> squash -> delta ----
__global__ __launch_bounds__(256) void k_route(const float* __restrict__ Bcur,
                                               const int*   __restrict__ seq_len,
                                               const float* __restrict__ low_new,
                                               float*       __restrict__ partials,
                                               float*       __restrict__ out,
                                               int do_delta, int do_out) {
    __shared__ float Wl[KCAPS * MAXLEN];   // logits -> softmax weights (in place)
    __shared__ float Hi[KCAPS * OUTU];     // squashed high
    const int b   = blockIdx.x;
    const int tid = threadIdx.x;
    const int len = seq_len[b];

    for (int i = tid; i < KCAPS * MAXLEN; i += 256) Wl[i] = Bcur[i];
    __syncthreads();

    // masked softmax, one half-wave (32 lanes) per k
    {
        const int k  = tid >> 5;
        const int ln = tid & 31;
        float m = -3.4e38f;
        for (int l = ln; l < MAXLEN; l += 32) {
            float v = (l < len) ? Wl[k * MAXLEN + l] : NEGPAD;
            m = fmaxf(m, v);
        }
        #pragma unroll
        for (int off = 16; off >= 1; off >>= 1) m = fmaxf(m, __shfl_xor(m, off));
        float ssum = 0.f;
        for (int l = ln; l < MAXLEN; l += 32) {
            float v = (l < len) ? Wl[k * MAXLEN + l] : NEGPAD;
            ssum += __expf(v - m);
        }
        #pragma unroll
        for (int off = 16; off >= 1; off >>= 1) ssum += __shfl_xor(ssum, off);
        float inv = 1.f / ssum;
        for (int l = ln; l < MAXLEN; l += 32) {
            float v = (l < len) ? Wl[k * MAXLEN + l] : NEGPAD;
            Wl[k * MAXLEN + l] = __expf(v - m) * inv;
        }
    }
    __syncthreads();

    // pass 1: high[k][o], thread <-> o
    const float* lb = low_new + (size_t)b * (MAXLEN * OUTU);
    float hk[KCAPS];
    #pragma unroll
    for (int k = 0; k < KCAPS; k++) hk[k] = 0.f;
    #pragma unroll 2
    for (int l4 = 0; l4 < MAXLEN; l4 += 4) {
        float v0 = lb[(l4 + 0) * OUTU + tid];
        float v1 = lb[(l4 + 1) * OUTU + tid];
        float v2 = lb[(l4 + 2) * OUTU + tid];
        float v3 = lb[(l4 + 3) * OUTU + tid];
        #pragma unroll
        for (int k = 0; k < KCAPS; k++) {
            const float4 w = *reinterpret_cast<const float4*>(&Wl[k * MAXLEN + l4]);
            hk[k] = fmaf(w.x, v0, hk[k]);
            hk[k] = fmaf(w.y, v1, hk[k]);
            hk[k] = fmaf(w.z, v2, hk[k]);
            hk[k] = fmaf(w.w, v3, hk[k]);
        }
    }
    // squash over k (thread-local: axis=1 of [B,K,O] is K)
    float n = 0.f;
    #pragma unroll
    for (int k = 0; k < KCAPS; k++) n = fmaf(hk[k], hk[k], n);
    float scale = n / (1.f + n) * (1.f / sqrtf(n + 1e-9f));

    if (do_out) {
        #pragma unroll
        for (int k = 0; k < KCAPS; k++)
            out[((size_t)b * KCAPS + k) * OUTU + tid] = scale * hk[k];
    }
    if (!do_delta) return;

    #pragma unroll
    for (int k = 0; k < KCAPS; k++) Hi[k * OUTU + tid] = scale * hk[k];
    __syncthreads();

    // pass 2: delta[k][l] = sum_o Hi[k][o] * low_new[b][l][o]; one wave per l
    const int wave = tid >> 6, lane = tid & 63;
    for (int l = wave; l < MAXLEN; l += 4) {
        float4 v = *reinterpret_cast<const float4*>(&lb[l * OUTU + lane * 4]);
        float p[KCAPS];
        #pragma unroll
        for (int k = 0; k < KCAPS; k++) {
            const float4 h = *reinterpret_cast<const float4*>(&Hi[k * OUTU + lane * 4]);
            p[k] = h.x * v.x + h.y * v.y + h.z * v.z + h.w * v.w;
        }
        #pragma unroll
        for (int off = 32; off >= 1; off >>= 1)
            #pragma unroll
            for (int k = 0; k < KCAPS; k++) p[k] += __shfl_xor(p[k], off);
        if (lane == 0) {
            #pragma unroll
            for (int k = 0; k < KCAPS; k++)
                partials[(size_t)(k * MAXLEN + l) * BATCH + b] = p[k];
        }
    }
}

// ---------------- B update: Bcur[i] += sum_b partials[i][b] (deterministic) -
__global__ __launch_bounds__(256) void k_update(const float* __restrict__ partials,
                                                float* __restrict__ Bcur) {
    __shared__ float red[256];
    const int i   = blockIdx.x;        // 0..1599
    const int tid = threadIdx.x;
    float s = 0.f;
    #pragma unroll
    for (int j = 0; j < BATCH / 256; j++) s += partials[(size_t)i * BATCH + tid + j * 256];
    red[tid] = s;
    __syncthreads();
    for (int st = 128; st > 0; st >>= 1) {
        if (tid < st) red[tid] += red[tid + st];
        __syncthreads();
    }
    if (tid == 0) Bcur[i] += red[0];
}

extern "C" void kernel_launch(void* const* d_in, const int* in_sizes, int n_in,
                              void* d_out, int out_size, void* d_ws, size_t ws_size,
                              hipStream_t stream) {
    const float* low = (const float*)d_in[0];
    const float* S   = (const float*)d_in[1];
    const float* Bm  = (const float*)d_in[2];
    const int*   seq = (const int*)d_in[3];
    float* out = (float*)d_out;

    char* ws = (char*)d_ws;
    float* low_new  = (float*)ws;                              // 1024*200*256*4 = 209,715,200 B
    float* Bcur     = (float*)(ws + 209715200);                // 6,400 B
    float* partials = (float*)(ws + 209715200 + 6400);         // 1600*1024*4 = 6,553,600 B

    k_init<<<(KCAPS * MAXLEN + 255) / 256, 256, 0, stream>>>(Bm, Bcur);
    k_project<<<3200, 256, 0, stream>>>(low, S, low_new);
    for (int it = 0; it < 3; it++) {
        int last = (it == 2);
        k_route<<<BATCH, 256, 0, stream>>>(Bcur, seq, low_new, partials, out,
                                           last ? 0 : 1, last ? 1 : 0);
        if (!last) k_update<<<KCAPS * MAXLEN, 256, 0, stream>>>(partials, Bcur);
    }
}

// Round 2
// 442.561 us; speedup vs baseline: 1.4839x; 1.4839x over previous
//
#include <hip/hip_runtime.h>

#define BATCH   1024
#define MAXLEN  200
#define KCAPS   8
#define INU     256
#define OUTU    256
#define NEGPAD  -65535.0f

typedef _Float16 f16;
typedef _Float16 f16x4 __attribute__((ext_vector_type(4)));
typedef _Float16 f16x8 __attribute__((ext_vector_type(8)));
typedef float    f32x4 __attribute__((ext_vector_type(4)));

// ---------------- init Bcur (copy B_matrix into workspace) ----------------
__global__ void k_init(const float* __restrict__ Bm, float* __restrict__ Bcur) {
    int i = blockIdx.x * 256 + threadIdx.x;
    if (i < KCAPS * MAXLEN) Bcur[i] = Bm[i];
}

// ---------------- split S (fp32) -> hi/lo fp16, packed in MFMA B-frag order
// packed idx = ((ks*16 + nf)*64 + lane)*8 + j  maps to S[ks*32 + (lane>>4)*8 + j][nf*16 + (lane&15)]
__global__ void k_convS(const float* __restrict__ S, f16* __restrict__ Shi, f16* __restrict__ Slo) {
    int idx = blockIdx.x * 256 + threadIdx.x;    // 0 .. 65535
    int j    = idx & 7;
    int lane = (idx >> 3) & 63;
    int nf   = (idx >> 9) & 15;
    int ks   = idx >> 13;
    int k = ks * 32 + (lane >> 4) * 8 + j;
    int n = nf * 16 + (lane & 15);
    float v = S[k * OUTU + n];
    f16 h = (f16)v;
    Shi[idx] = h;
    Slo[idx] = (f16)(v - (float)h);
}

// ---------------- projection via split-fp16 MFMA ---------------------------
// C[M,256] = A[M,256] @ S[256,256], M = 204800. Block tile 128x256, 8 waves,
// wave tile 64x64 (4x4 frags of 16x16).  A·S ≈ Ah·Sh + Al·Sh + Ah·Sl.
#define LDA 40   // halves per LDS row (32 + 8 pad)

__global__ __launch_bounds__(512) void k_project_mfma(const float* __restrict__ A,
                                                      const f16* __restrict__ Shi,
                                                      const f16* __restrict__ Slo,
                                                      float* __restrict__ C) {
    __shared__ f16 Ah[128 * LDA];
    __shared__ f16 Al[128 * LDA];
    const int tid  = threadIdx.x;
    const int wave = tid >> 6, lane = tid & 63;
    const int wm = wave >> 2, wn = wave & 3;           // wm 0..1, wn 0..3
    const size_t m0 = (size_t)blockIdx.x * 128;

    f32x4 acc[4][4];
    #pragma unroll
    for (int a = 0; a < 4; a++)
        #pragma unroll
        for (int b = 0; b < 4; b++)
            acc[a][b] = (f32x4){0.f, 0.f, 0.f, 0.f};

    for (int ks = 0; ks < 8; ks++) {
        __syncthreads();
        // stage A tile 128x32 fp32 -> hi/lo fp16 in LDS
        #pragma unroll
        for (int i = 0; i < 2; i++) {
            int f4  = tid + i * 512;                   // 0..1023
            int row = f4 >> 3, c4 = f4 & 7;
            float4 v = *reinterpret_cast<const float4*>(&A[(m0 + row) * INU + ks * 32 + c4 * 4]);
            f16x4 h  = { (f16)v.x, (f16)v.y, (f16)v.z, (f16)v.w };
            f16x4 lo = { (f16)(v.x - (float)h[0]), (f16)(v.y - (float)h[1]),
                         (f16)(v.z - (float)h[2]), (f16)(v.w - (float)h[3]) };
            *reinterpret_cast<f16x4*>(&Ah[row * LDA + c4 * 4]) = h;
            *reinterpret_cast<f16x4*>(&Al[row * LDA + c4 * 4]) = lo;
        }
        __syncthreads();

        // B fragments from global (L2-resident, packed layout -> coalesced)
        f16x8 bh[4], bl[4];
        #pragma unroll
        for (int nf4 = 0; nf4 < 4; nf4++) {
            int nf = wn * 4 + nf4;
            bh[nf4] = *reinterpret_cast<const f16x8*>(&Shi[((ks * 16 + nf) * 64 + lane) * 8]);
            bl[nf4] = *reinterpret_cast<const f16x8*>(&Slo[((ks * 16 + nf) * 64 + lane) * 8]);
        }
        // A fragments from LDS
        f16x8 ah[4], al[4];
        const int koff = (lane >> 4) * 8;
        #pragma unroll
        for (int mf = 0; mf < 4; mf++) {
            int row = wm * 64 + mf * 16 + (lane & 15);
            ah[mf] = *reinterpret_cast<const f16x8*>(&Ah[row * LDA + koff]);
            al[mf] = *reinterpret_cast<const f16x8*>(&Al[row * LDA + koff]);
        }
        #pragma unroll
        for (int mf = 0; mf < 4; mf++)
            #pragma unroll
            for (int nf = 0; nf < 4; nf++) {
                acc[mf][nf] = __builtin_amdgcn_mfma_f32_16x16x32_f16(ah[mf], bh[nf], acc[mf][nf], 0, 0, 0);
                acc[mf][nf] = __builtin_amdgcn_mfma_f32_16x16x32_f16(al[mf], bh[nf], acc[mf][nf], 0, 0, 0);
                acc[mf][nf] = __builtin_amdgcn_mfma_f32_16x16x32_f16(ah[mf], bl[nf], acc[mf][nf], 0, 0, 0);
            }
    }

    // epilogue: C[row = m0 + wm*64 + mf*16 + (lane>>4)*4 + r][col = wn*64 + nf*16 + (lane&15)]
    #pragma unroll
    for (int mf = 0; mf < 4; mf++) {
        size_t rbase = m0 + wm * 64 + mf * 16 + ((lane >> 4) * 4);
        #pragma unroll
        for (int nf = 0; nf < 4; nf++) {
            int c = wn * 64 + nf * 16 + (lane & 15);
            #pragma unroll
            for (int r = 0; r < 4; r++)
                C[(rbase + r) * OUTU + c] = acc[mf][nf][r];
        }
    }
}

// ---------------- routing iteration: softmax -> high -> squash -> delta ----
__global__ __launch_bounds__(256) void k_route(const float* __restrict__ Bcur,
                                               const int*   __restrict__ seq_len,
                                               const float* __restrict__ low_new,
                                               float*       __restrict__ partials,
                                               float*       __restrict__ out,
                                               int do_delta, int do_out) {
    __shared__ float Wl[KCAPS * MAXLEN];   // logits -> softmax weights (in place)
    __shared__ float Hi[KCAPS * OUTU];     // squashed high
    const int b   = blockIdx.x;
    const int tid = threadIdx.x;
    const int len = seq_len[b];

    for (int i = tid; i < KCAPS * MAXLEN; i += 256) Wl[i] = Bcur[i];
    __syncthreads();

    // masked softmax, one half-wave (32 lanes) per k
    {
        const int k  = tid >> 5;
        const int ln = tid & 31;
        float m = -3.4e38f;
        for (int l = ln; l < MAXLEN; l += 32) {
            float v = (l < len) ? Wl[k * MAXLEN + l] : NEGPAD;
            m = fmaxf(m, v);
        }
        #pragma unroll
        for (int off = 16; off >= 1; off >>= 1) m = fmaxf(m, __shfl_xor(m, off));
        float ssum = 0.f;
        for (int l = ln; l < MAXLEN; l += 32) {
            float v = (l < len) ? Wl[k * MAXLEN + l] : NEGPAD;
            ssum += __expf(v - m);
        }
        #pragma unroll
        for (int off = 16; off >= 1; off >>= 1) ssum += __shfl_xor(ssum, off);
        float inv = 1.f / ssum;
        for (int l = ln; l < MAXLEN; l += 32) {
            float v = (l < len) ? Wl[k * MAXLEN + l] : NEGPAD;
            Wl[k * MAXLEN + l] = __expf(v - m) * inv;
        }
    }
    __syncthreads();

    // pass 1: high[k][o], thread <-> o
    const float* lb = low_new + (size_t)b * (MAXLEN * OUTU);
    float hk[KCAPS];
    #pragma unroll
    for (int k = 0; k < KCAPS; k++) hk[k] = 0.f;
    #pragma unroll 2
    for (int l4 = 0; l4 < MAXLEN; l4 += 4) {
        float v0 = lb[(l4 + 0) * OUTU + tid];
        float v1 = lb[(l4 + 1) * OUTU + tid];
        float v2 = lb[(l4 + 2) * OUTU + tid];
        float v3 = lb[(l4 + 3) * OUTU + tid];
        #pragma unroll
        for (int k = 0; k < KCAPS; k++) {
            const float4 w = *reinterpret_cast<const float4*>(&Wl[k * MAXLEN + l4]);
            hk[k] = fmaf(w.x, v0, hk[k]);
            hk[k] = fmaf(w.y, v1, hk[k]);
            hk[k] = fmaf(w.z, v2, hk[k]);
            hk[k] = fmaf(w.w, v3, hk[k]);
        }
    }
    // squash over k (thread-local: axis=1 of [B,K,O] is K)
    float n = 0.f;
    #pragma unroll
    for (int k = 0; k < KCAPS; k++) n = fmaf(hk[k], hk[k], n);
    float scale = n / (1.f + n) * (1.f / sqrtf(n + 1e-9f));

    if (do_out) {
        #pragma unroll
        for (int k = 0; k < KCAPS; k++)
            out[((size_t)b * KCAPS + k) * OUTU + tid] = scale * hk[k];
    }
    if (!do_delta) return;

    #pragma unroll
    for (int k = 0; k < KCAPS; k++) Hi[k * OUTU + tid] = scale * hk[k];
    __syncthreads();

    // pass 2: delta[k][l] = sum_o Hi[k][o] * low_new[b][l][o]; one wave per l
    const int wave = tid >> 6, lane = tid & 63;
    for (int l = wave; l < MAXLEN; l += 4) {
        float4 v = *reinterpret_cast<const float4*>(&lb[l * OUTU + lane * 4]);
        float p[KCAPS];
        #pragma unroll
        for (int k = 0; k < KCAPS; k++) {
            const float4 h = *reinterpret_cast<const float4*>(&Hi[k * OUTU + lane * 4]);
            p[k] = h.x * v.x + h.y * v.y + h.z * v.z + h.w * v.w;
        }
        #pragma unroll
        for (int off = 32; off >= 1; off >>= 1)
            #pragma unroll
            for (int k = 0; k < KCAPS; k++) p[k] += __shfl_xor(p[k], off);
        if (lane == 0) {
            #pragma unroll
            for (int k = 0; k < KCAPS; k++)
                partials[(size_t)(k * MAXLEN + l) * BATCH + b] = p[k];
        }
    }
}

// ---------------- B update: Bcur[i] += sum_b partials[i][b] (deterministic) -
__global__ __launch_bounds__(256) void k_update(const float* __restrict__ partials,
                                                float* __restrict__ Bcur) {
    __shared__ float red[256];
    const int i   = blockIdx.x;        // 0..1599
    const int tid = threadIdx.x;
    float s = 0.f;
    #pragma unroll
    for (int j = 0; j < BATCH / 256; j++) s += partials[(size_t)i * BATCH + tid + j * 256];
    red[tid] = s;
    __syncthreads();
    for (int st = 128; st > 0; st >>= 1) {
        if (tid < st) red[tid] += red[tid + st];
        __syncthreads();
    }
    if (tid == 0) Bcur[i] += red[0];
}

extern "C" void kernel_launch(void* const* d_in, const int* in_sizes, int n_in,
                              void* d_out, int out_size, void* d_ws, size_t ws_size,
                              hipStream_t stream) {
    const float* low = (const float*)d_in[0];
    const float* S   = (const float*)d_in[1];
    const float* Bm  = (const float*)d_in[2];
    const int*   seq = (const int*)d_in[3];
    float* out = (float*)d_out;

    char* ws = (char*)d_ws;
    float* low_new  = (float*)ws;                              // 209,715,200 B
    float* Bcur     = (float*)(ws + 209715200);                // 6,400 B
    float* partials = (float*)(ws + 209721600);                // 6,553,600 B
    // S_hi/S_lo packed live in the partials region (only needed during projection,
    // partials is rewritten by k_route afterwards) -> no extra ws.
    f16* Shi = (f16*)(ws + 209721600);                         // 131,072 B
    f16* Slo = (f16*)(ws + 209721600 + 131072);                // 131,072 B

    k_init<<<(KCAPS * MAXLEN + 255) / 256, 256, 0, stream>>>(Bm, Bcur);
    k_convS<<<256, 256, 0, stream>>>(S, Shi, Slo);
    k_project_mfma<<<1600, 512, 0, stream>>>(low, Shi, Slo, low_new);
    for (int it = 0; it < 3; it++) {
        int last = (it == 2);
        k_route<<<BATCH, 256, 0, stream>>>(Bcur, seq, low_new, partials, out,
                                           last ? 0 : 1, last ? 1 : 0);
        if (!last) k_update<<<KCAPS * MAXLEN, 256, 0, stream>>>(partials, Bcur);
    }
}

// Round 3
// 321.638 us; speedup vs baseline: 2.0419x; 1.3760x over previous
//
#include <hip/hip_runtime.h>

#define BATCH   1024
#define MAXLEN  200
#define KCAPS   8
#define INU     256
#define OUTU    256
#define NEGPAD  -65535.0f
#define HSTR    264   // Hi LDS row stride (floats): 8*33 -> spreads banks, 16B aligned

typedef _Float16 f16;
typedef _Float16 f16x4 __attribute__((ext_vector_type(4)));
typedef _Float16 f16x8 __attribute__((ext_vector_type(8)));
typedef float    f32x4 __attribute__((ext_vector_type(4)));

// ---------------- init Bcur (copy B_matrix into workspace) ----------------
__global__ void k_init(const float* __restrict__ Bm, float* __restrict__ Bcur) {
    int i = blockIdx.x * 256 + threadIdx.x;
    if (i < KCAPS * MAXLEN) Bcur[i] = Bm[i];
}

// ---------------- split S (fp32) -> hi/lo fp16, packed in MFMA B-frag order
__global__ void k_convS(const float* __restrict__ S, f16* __restrict__ Shi, f16* __restrict__ Slo) {
    int idx = blockIdx.x * 256 + threadIdx.x;    // 0 .. 65535
    int j    = idx & 7;
    int lane = (idx >> 3) & 63;
    int nf   = (idx >> 9) & 15;
    int ks   = idx >> 13;
    int k = ks * 32 + (lane >> 4) * 8 + j;
    int n = nf * 16 + (lane & 15);
    float v = S[k * OUTU + n];
    f16 h = (f16)v;
    Shi[idx] = h;
    Slo[idx] = (f16)(v - (float)h);
}

// ---------------- projection via split-fp16 MFMA ---------------------------
#define LDA 40   // halves per LDS row (32 + 8 pad)

__global__ __launch_bounds__(512) void k_project_mfma(const float* __restrict__ A,
                                                      const f16* __restrict__ Shi,
                                                      const f16* __restrict__ Slo,
                                                      float* __restrict__ C) {
    __shared__ f16 Ah[128 * LDA];
    __shared__ f16 Al[128 * LDA];
    const int tid  = threadIdx.x;
    const int wave = tid >> 6, lane = tid & 63;
    const int wm = wave >> 2, wn = wave & 3;
    const size_t m0 = (size_t)blockIdx.x * 128;

    f32x4 acc[4][4];
    #pragma unroll
    for (int a = 0; a < 4; a++)
        #pragma unroll
        for (int b = 0; b < 4; b++)
            acc[a][b] = (f32x4){0.f, 0.f, 0.f, 0.f};

    for (int ks = 0; ks < 8; ks++) {
        __syncthreads();
        #pragma unroll
        for (int i = 0; i < 2; i++) {
            int f4  = tid + i * 512;
            int row = f4 >> 3, c4 = f4 & 7;
            float4 v = *reinterpret_cast<const float4*>(&A[(m0 + row) * INU + ks * 32 + c4 * 4]);
            f16x4 h  = { (f16)v.x, (f16)v.y, (f16)v.z, (f16)v.w };
            f16x4 lo = { (f16)(v.x - (float)h[0]), (f16)(v.y - (float)h[1]),
                         (f16)(v.z - (float)h[2]), (f16)(v.w - (float)h[3]) };
            *reinterpret_cast<f16x4*>(&Ah[row * LDA + c4 * 4]) = h;
            *reinterpret_cast<f16x4*>(&Al[row * LDA + c4 * 4]) = lo;
        }
        __syncthreads();

        f16x8 bh[4], bl[4];
        #pragma unroll
        for (int nf4 = 0; nf4 < 4; nf4++) {
            int nf = wn * 4 + nf4;
            bh[nf4] = *reinterpret_cast<const f16x8*>(&Shi[((ks * 16 + nf) * 64 + lane) * 8]);
            bl[nf4] = *reinterpret_cast<const f16x8*>(&Slo[((ks * 16 + nf) * 64 + lane) * 8]);
        }
        f16x8 ah[4], al[4];
        const int koff = (lane >> 4) * 8;
        #pragma unroll
        for (int mf = 0; mf < 4; mf++) {
            int row = wm * 64 + mf * 16 + (lane & 15);
            ah[mf] = *reinterpret_cast<const f16x8*>(&Ah[row * LDA + koff]);
            al[mf] = *reinterpret_cast<const f16x8*>(&Al[row * LDA + koff]);
        }
        #pragma unroll
        for (int mf = 0; mf < 4; mf++)
            #pragma unroll
            for (int nf = 0; nf < 4; nf++) {
                acc[mf][nf] = __builtin_amdgcn_mfma_f32_16x16x32_f16(ah[mf], bh[nf], acc[mf][nf], 0, 0, 0);
                acc[mf][nf] = __builtin_amdgcn_mfma_f32_16x16x32_f16(al[mf], bh[nf], acc[mf][nf], 0, 0, 0);
                acc[mf][nf] = __builtin_amdgcn_mfma_f32_16x16x32_f16(ah[mf], bl[nf], acc[mf][nf], 0, 0, 0);
            }
    }

    #pragma unroll
    for (int mf = 0; mf < 4; mf++) {
        size_t rbase = m0 + wm * 64 + mf * 16 + ((lane >> 4) * 4);
        #pragma unroll
        for (int nf = 0; nf < 4; nf++) {
            int c = wn * 64 + nf * 16 + (lane & 15);
            #pragma unroll
            for (int r = 0; r < 4; r++)
                C[(rbase + r) * OUTU + c] = acc[mf][nf][r];
        }
    }
}

// ---------------- routing iteration: softmax -> high -> squash -> delta ----
__global__ __launch_bounds__(256) void k_route(const float* __restrict__ Bcur,
                                               const int*   __restrict__ seq_len,
                                               const float* __restrict__ low_new,
                                               float*       __restrict__ partials,
                                               float*       __restrict__ out,
                                               int do_delta, int do_out) {
    __shared__ float Wl[KCAPS * MAXLEN];   // logits -> softmax weights (in place)
    __shared__ float Hi[16 * HSTR];        // squashed high, 16 rows (8 real + 8 zero pad)
    const int b   = blockIdx.x;
    const int tid = threadIdx.x;
    const int len = seq_len[b];

    for (int i = tid; i < KCAPS * MAXLEN; i += 256) Wl[i] = Bcur[i];
    // zero Hi (incl. pad rows 8..15 and pad cols) while logits load
    for (int i = tid; i < 16 * HSTR; i += 256) Hi[i] = 0.f;
    __syncthreads();

    // masked softmax, one half-wave (32 lanes) per k
    {
        const int k  = tid >> 5;
        const int ln = tid & 31;
        float m = -3.4e38f;
        for (int l = ln; l < MAXLEN; l += 32) {
            float v = (l < len) ? Wl[k * MAXLEN + l] : NEGPAD;
            m = fmaxf(m, v);
        }
        #pragma unroll
        for (int off = 16; off >= 1; off >>= 1) m = fmaxf(m, __shfl_xor(m, off));
        float ssum = 0.f;
        for (int l = ln; l < MAXLEN; l += 32) {
            float v = (l < len) ? Wl[k * MAXLEN + l] : NEGPAD;
            ssum += __expf(v - m);
        }
        #pragma unroll
        for (int off = 16; off >= 1; off >>= 1) ssum += __shfl_xor(ssum, off);
        float inv = 1.f / ssum;
        for (int l = ln; l < MAXLEN; l += 32) {
            float v = (l < len) ? Wl[k * MAXLEN + l] : NEGPAD;
            Wl[k * MAXLEN + l] = __expf(v - m) * inv;
        }
    }
    __syncthreads();

    // pass 1: high[k][o], thread <-> o  (VALU, o-parallel)
    const float* lb = low_new + (size_t)b * (MAXLEN * OUTU);
    float hk[KCAPS];
    #pragma unroll
    for (int k = 0; k < KCAPS; k++) hk[k] = 0.f;
    #pragma unroll 2
    for (int l4 = 0; l4 < MAXLEN; l4 += 4) {
        float v0 = lb[(l4 + 0) * OUTU + tid];
        float v1 = lb[(l4 + 1) * OUTU + tid];
        float v2 = lb[(l4 + 2) * OUTU + tid];
        float v3 = lb[(l4 + 3) * OUTU + tid];
        #pragma unroll
        for (int k = 0; k < KCAPS; k++) {
            const float4 w = *reinterpret_cast<const float4*>(&Wl[k * MAXLEN + l4]);
            hk[k] = fmaf(w.x, v0, hk[k]);
            hk[k] = fmaf(w.y, v1, hk[k]);
            hk[k] = fmaf(w.z, v2, hk[k]);
            hk[k] = fmaf(w.w, v3, hk[k]);
        }
    }
    float n = 0.f;
    #pragma unroll
    for (int k = 0; k < KCAPS; k++) n = fmaf(hk[k], hk[k], n);
    float scale = n / (1.f + n) * (1.f / sqrtf(n + 1e-9f));

    if (do_out) {
        #pragma unroll
        for (int k = 0; k < KCAPS; k++)
            out[((size_t)b * KCAPS + k) * OUTU + tid] = scale * hk[k];
    }
    if (!do_delta) return;

    __syncthreads();   // Hi zero-fill (other threads) must complete before row writes
    #pragma unroll
    for (int k = 0; k < KCAPS; k++) Hi[k * HSTR + tid] = scale * hk[k];
    __syncthreads();

    // pass 2 (MFMA): delta_T[l][k] = sum_o low[l][o] * high[k][o]
    // A = low rows (global fp32 -> f16 hi/lo), B = Hi^T frags from LDS.
    const int wave = tid >> 6, lane = tid & 63;
    const int nfr = (wave == 0) ? 4 : 3;      // M-frags: wave, wave+4, wave+8, (+12 for wave 0)
    f32x4 acc2[4];
    #pragma unroll
    for (int i = 0; i < 4; i++) acc2[i] = (f32x4){0.f, 0.f, 0.f, 0.f};

    for (int ks = 0; ks < 8; ks++) {
        const int ob = ks * 32 + ((lane >> 4) * 8);
        // B frag: element B[kk][n] = Hi[n][ks*32 + kk], kk=(lane>>4)*8+j, n=lane&15
        f32x4 h0 = *reinterpret_cast<const f32x4*>(&Hi[(lane & 15) * HSTR + ob]);
        f32x4 h1 = *reinterpret_cast<const f32x4*>(&Hi[(lane & 15) * HSTR + ob + 4]);
        f16x8 bh, bl;
        #pragma unroll
        for (int j = 0; j < 4; j++) {
            f16 t = (f16)h0[j]; bh[j] = t; bl[j] = (f16)(h0[j] - (float)t);
        }
        #pragma unroll
        for (int j = 0; j < 4; j++) {
            f16 t = (f16)h1[j]; bh[4 + j] = t; bl[4 + j] = (f16)(h1[j] - (float)t);
        }
        for (int mi = 0; mi < nfr; mi++) {
            const int mf = wave + mi * 4;
            const int l  = mf * 16 + (lane & 15);      // may exceed 199: garbage row, unwritten
            const float* ap = lb + (size_t)l * OUTU + ob;
            float4 v0 = *reinterpret_cast<const float4*>(ap);
            float4 v1 = *reinterpret_cast<const float4*>(ap + 4);
            f16x8 ah, al;
            ah[0] = (f16)v0.x; al[0] = (f16)(v0.x - (float)ah[0]);
            ah[1] = (f16)v0.y; al[1] = (f16)(v0.y - (float)ah[1]);
            ah[2] = (f16)v0.z; al[2] = (f16)(v0.z - (float)ah[2]);
            ah[3] = (f16)v0.w; al[3] = (f16)(v0.w - (float)ah[3]);
            ah[4] = (f16)v1.x; al[4] = (f16)(v1.x - (float)ah[4]);
            ah[5] = (f16)v1.y; al[5] = (f16)(v1.y - (float)ah[5]);
            ah[6] = (f16)v1.z; al[6] = (f16)(v1.z - (float)ah[6]);
            ah[7] = (f16)v1.w; al[7] = (f16)(v1.w - (float)ah[7]);
            acc2[mi] = __builtin_amdgcn_mfma_f32_16x16x32_f16(ah, bh, acc2[mi], 0, 0, 0);
            acc2[mi] = __builtin_amdgcn_mfma_f32_16x16x32_f16(al, bh, acc2[mi], 0, 0, 0);
            acc2[mi] = __builtin_amdgcn_mfma_f32_16x16x32_f16(ah, bl, acc2[mi], 0, 0, 0);
        }
    }
    // write: D col = lane&15 (= k, keep <8), D rows = mf*16 + (lane>>4)*4 + r (= l, keep <200)
    const int kcol = lane & 15;
    if (kcol < KCAPS) {
        for (int mi = 0; mi < nfr; mi++) {
            const int mf = wave + mi * 4;
            const int lbase = mf * 16 + ((lane >> 4) * 4);
            #pragma unroll
            for (int r = 0; r < 4; r++) {
                const int l = lbase + r;
                if (l < MAXLEN)
                    partials[(size_t)(kcol * MAXLEN + l) * BATCH + b] = acc2[mi][r];
            }
        }
    }
}

// ---------------- B update: Bcur[i] += sum_b partials[i][b] (deterministic) -
__global__ __launch_bounds__(256) void k_update(const float* __restrict__ partials,
                                                float* __restrict__ Bcur) {
    __shared__ float red[256];
    const int i   = blockIdx.x;
    const int tid = threadIdx.x;
    float s = 0.f;
    #pragma unroll
    for (int j = 0; j < BATCH / 256; j++) s += partials[(size_t)i * BATCH + tid + j * 256];
    red[tid] = s;
    __syncthreads();
    for (int st = 128; st > 0; st >>= 1) {
        if (tid < st) red[tid] += red[tid + st];
        __syncthreads();
    }
    if (tid == 0) Bcur[i] += red[0];
}

extern "C" void kernel_launch(void* const* d_in, const int* in_sizes, int n_in,
                              void* d_out, int out_size, void* d_ws, size_t ws_size,
                              hipStream_t stream) {
    const float* low = (const float*)d_in[0];
    const float* S   = (const float*)d_in[1];
    const float* Bm  = (const float*)d_in[2];
    const int*   seq = (const int*)d_in[3];
    float* out = (float*)d_out;

    char* ws = (char*)d_ws;
    float* low_new  = (float*)ws;                              // 209,715,200 B
    float* Bcur     = (float*)(ws + 209715200);                // 6,400 B
    float* partials = (float*)(ws + 209721600);                // 6,553,600 B
    f16* Shi = (f16*)(ws + 209721600);                         // aliases partials (projection-only)
    f16* Slo = (f16*)(ws + 209721600 + 131072);

    k_init<<<(KCAPS * MAXLEN + 255) / 256, 256, 0, stream>>>(Bm, Bcur);
    k_convS<<<256, 256, 0, stream>>>(S, Shi, Slo);
    k_project_mfma<<<1600, 512, 0, stream>>>(low, Shi, Slo, low_new);
    for (int it = 0; it < 3; it++) {
        int last = (it == 2);
        k_route<<<BATCH, 256, 0, stream>>>(Bcur, seq, low_new, partials, out,
                                           last ? 0 : 1, last ? 1 : 0);
        if (!last) k_update<<<KCAPS * MAXLEN, 256, 0, stream>>>(partials, Bcur);
    }
}